// Round 4
// baseline (217.609 us; speedup 1.0000x reference)
//
#include <hip/hip_runtime.h>

typedef _Float16 half8 __attribute__((ext_vector_type(8)));
typedef float f32x16 __attribute__((ext_vector_type(16)));
typedef float f32x4 __attribute__((ext_vector_type(4)));

#define N_IMG 32
#define C_IN  128
#define H_IN  56
#define W_IN  56
#define F_OUT 256
#define HO    54
#define WO    54
#define KKDIM 1152
#define NKB   18            // 1152 / 64

// ws layout: T2 (fp16, swizzled NWHC) then Bp (fp16, swizzled weights)
#define T2_BYTES (N_IMG * W_IN * H_IN * C_IN * 2)   // 25,690,112
#define BP_OFF   T2_BYTES
#define BP_BYTES (NKB * F_OUT * 64 * 2)             // 589,824
#define WS_NEED  (BP_OFF + BP_BYTES)

#define SLAB_I_STRIDE 14336        // 56 rows * 256 B
#define A_BYTES  (6 * SLAB_I_STRIDE)   // 86016
#define B_CHUNK  32768
#define SMEM_BYTES (A_BYTES + 2 * B_CHUNK)  // 151552 (needs hipFuncSetAttribute)

// ---------------------------------------------------------------------------
// Kernel 1: inputs NCHW fp32 -> T2[n][ww][hh][c] fp16, XOR-swizzled per row:
// within each 256B c-row, 16B block index ^= (hh & 15). One block per (n,hh).
// Swizzle baked into GLOBAL layout so k_gemm can stage via linear
// global_load_lds (rule 21: linear LDS dest + pre-swizzled source).
// ---------------------------------------------------------------------------
__global__ __launch_bounds__(256) void k_transpose(const float* __restrict__ in,
                                                   _Float16* __restrict__ t2) {
    __shared__ _Float16 Lt[128 * 57];
    const int n  = blockIdx.y;
    const int hh = blockIdx.x;
    const int t  = threadIdx.x;

    // Phase A: coalesced read of inputs[n][c][hh][0..55], cast to fp16 in LDS
    {
        const int ww = t & 63;
        const int c0 = t >> 6;
        if (ww < 56) {
            for (int c = c0; c < 128; c += 4)
                Lt[c * 57 + ww] = (_Float16)in[(((size_t)(n * 128 + c) * 56) + hh) * 56 + ww];
        }
    }
    __syncthreads();

    // Phase B: write T2 rows, 16B packed stores; wave writes 4x256B segments
    {
        const int ci  = t & 15;        // c-block of 8
        const int wwi = t >> 4;        // 0..15
        const int X   = (hh & 15) << 4;
        for (int ww = wwi; ww < 56; ww += 16) {
            union { _Float16 h[8]; int4 v; } u;
#pragma unroll
            for (int jj = 0; jj < 8; ++jj)
                u.h[jj] = Lt[(ci * 8 + jj) * 57 + ww];
            char* dst = (char*)t2 + ((size_t)((n * 56 + ww) * 56 + hh)) * 256 + ((ci * 16) ^ X);
            *(int4*)dst = u.v;
        }
    }
}

// ---------------------------------------------------------------------------
// Kernel 2: weights fp32 [F][1152] -> Bp[kb][f][kin] fp16, row swizzle (f&7)<<4
// kb = k/64 = (i*3+j)*2 + c/64 -- matches k_gemm's ij = kb>>1, ch2 = (kb&1)*128B
// ---------------------------------------------------------------------------
__global__ __launch_bounds__(256) void k_weights(const float* __restrict__ kern,
                                                 _Float16* __restrict__ bp) {
    const int tid = blockIdx.x * 256 + threadIdx.x;
    if (tid >= F_OUT * KKDIM) return;
    const int f = tid / KKDIM;
    const int k = tid % KKDIM;
    const int kb = k >> 6, kin = k & 63;
    const _Float16 v = (_Float16)kern[tid];
    char* dst = (char*)bp + kb * B_CHUNK + f * 128 + ((kin * 2) ^ ((f & 7) << 4));
    *(_Float16*)dst = v;
}

// ---------------------------------------------------------------------------
// Kernel 3: implicit-GEMM MFMA. WG = (n, 4 w-cols) -> 256(M=4w x 64h) x 256(f).
// 8 waves: wave (wm, wf) owns w-col wm, f-half wf: 64h x 128f via 32x32x16 f16.
// A slab [6 ww][56 hh][128 c] resident (84KB), B double-buffered K=64 chunks.
// 2-phase schedule (T3-minimum): issue next-B prefetch, compute current,
// one implicit vmcnt(0)+barrier per K-chunk (from __syncthreads).
// ---------------------------------------------------------------------------
typedef const __attribute__((address_space(1))) unsigned int guint;
typedef __attribute__((address_space(3))) unsigned int luint;

__global__ __launch_bounds__(512, 2) void k_gemm(const _Float16* __restrict__ t2,
                                                 const _Float16* __restrict__ bp,
                                                 float* __restrict__ out) {
    extern __shared__ char smem[];
    char* As  = smem;
    char* Bs0 = smem + A_BYTES;
    char* Bs1 = smem + A_BYTES + B_CHUNK;

    const int tid  = threadIdx.x;
    const int lane = tid & 63;
    const int wid  = tid >> 6;       // 0..7
    const int wm   = wid >> 1;       // w-col within block, 0..3
    const int wf   = wid & 1;        // f half
    const int ln31 = lane & 31;
    const int kin2 = (lane >> 5) * 16;   // byte offset of lane-half within k16
    const int n  = blockIdx.y;
    const int w0 = blockIdx.x * 4;

    // ---- stage A slab (linear copy of pre-swizzled T2 chunk) ----
    // navail clamp: at w0=52 only 4 rows exist; stage ends exactly at T2's end.
    int navail = 56 - w0; if (navail > 6) navail = 6;
    const int bytesA = navail * SLAB_I_STRIDE;
    const char* t2n = (const char*)t2 + (size_t)(n * 56 + w0) * 56 * 256;
    for (int o = tid * 16; o < bytesA; o += 8192)
        __builtin_amdgcn_global_load_lds((guint*)(t2n + o), (luint*)(As + o), 16, 0, 0);

    // ---- stage B chunk 0 ----
    const char* bpc = (const char*)bp;
    for (int o = tid * 16; o < B_CHUNK; o += 8192)
        __builtin_amdgcn_global_load_lds((guint*)(bpc + o), (luint*)(Bs0 + o), 16, 0, 0);

    f32x16 acc[2][4];
#pragma unroll
    for (int m2 = 0; m2 < 2; ++m2)
#pragma unroll
        for (int ft = 0; ft < 4; ++ft)
#pragma unroll
            for (int e = 0; e < 16; ++e)
                acc[m2][ft][e] = 0.0f;

    __syncthreads();   // drains vmcnt(0): A slab + B0 resident

    for (int kb = 0; kb < NKB; ++kb) {
        char* curB = (kb & 1) ? Bs1 : Bs0;
        if (kb < NKB - 1) {
            // prefetch next B chunk; its buffer's readers retired at the
            // barrier that ended iteration kb-1 (no race)
            char* nxtB = (kb & 1) ? Bs0 : Bs1;
            const char* src = bpc + (kb + 1) * B_CHUNK;
#pragma unroll
            for (int oi = 0; oi < 4; ++oi) {
                int o = tid * 16 + oi * 8192;
                __builtin_amdgcn_global_load_lds((guint*)(src + o), (luint*)(nxtB + o), 16, 0, 0);
            }
        }

        const int ij  = kb >> 1;
        const int iq  = ij / 3;            // w-offset
        const int jq  = ij - iq * 3;       // h-offset
        const int ch2 = (kb & 1) * 128;    // c byte offset of this 64-k chunk
        const int iwb = (wm + iq) * SLAB_I_STRIDE;
        const int hh0 = ln31 + jq;
        const int Xa  = (hh0 & 15) << 4;   // m2*32 doesn't change &15
        const int Xb  = (ln31 & 7) << 4;

#pragma unroll
        for (int s = 0; s < 4; ++s) {
            const int cb = ch2 + s * 32 + kin2;   // byte offset within 256B c-row
            half8 aF[2];
#pragma unroll
            for (int m2 = 0; m2 < 2; ++m2) {
                const int hh = hh0 + m2 * 32;
                aF[m2] = *(const half8*)(As + iwb + hh * 256 + (cb ^ Xa));
            }
            half8 bF[4];
#pragma unroll
            for (int ft = 0; ft < 4; ++ft) {
                const int f = wf * 128 + ft * 32 + ln31;
                bF[ft] = *(const half8*)(curB + f * 128 + ((s * 32 + kin2) ^ Xb));
            }
#pragma unroll
            for (int m2 = 0; m2 < 2; ++m2)
#pragma unroll
                for (int ft = 0; ft < 4; ++ft)
                    acc[m2][ft] = __builtin_amdgcn_mfma_f32_32x32x16_f16(aF[m2], bF[ft], acc[m2][ft], 0, 0, 0);
        }
        __syncthreads();
    }

    // ---- epilogue: C/D layout col=lane&31(f), row=(reg&3)+8*(reg>>2)+4*(lane>>5)
    const int w = w0 + wm;
    if (w < WO) {
        const int hi4 = (lane >> 5) * 4;
#pragma unroll
        for (int m2 = 0; m2 < 2; ++m2) {
#pragma unroll
            for (int ft = 0; ft < 4; ++ft) {
                const int f = wf * 128 + ft * 32 + ln31;
                float* op = out + ((size_t)(n * 256 + f) * 54 + w) * 54;
#pragma unroll
                for (int q = 0; q < 4; ++q) {
                    const int hb = m2 * 32 + q * 8 + hi4;
                    if (hb + 3 < HO) {
                        f32x4 v = { acc[m2][ft][4 * q + 0], acc[m2][ft][4 * q + 1],
                                    acc[m2][ft][4 * q + 2], acc[m2][ft][4 * q + 3] };
                        *(f32x4*)(op + hb) = v;
                    } else if (hb < HO) {   // hb == 52
                        op[hb]     = acc[m2][ft][4 * q + 0];
                        op[hb + 1] = acc[m2][ft][4 * q + 1];
                    }
                }
            }
        }
    }
}

// ---------------------------------------------------------------------------
// Fallback (only if ws too small): naive direct conv, correct but slow.
// ---------------------------------------------------------------------------
__global__ __launch_bounds__(256) void k_naive(const float* __restrict__ in,
                                               const float* __restrict__ kern,
                                               float* __restrict__ out) {
    const int idx = blockIdx.x * 256 + threadIdx.x;
    const int total = N_IMG * F_OUT * WO * HO;
    if (idx >= total) return;
    const int h = idx % 54;
    const int w = (idx / 54) % 54;
    const int f = (idx / (54 * 54)) % 256;
    const int n = idx / (54 * 54 * 256);
    float s = 0.f;
    for (int ij = 0; ij < 9; ++ij) {
        const int i = ij / 3, j = ij % 3;
        const float* ip = in + ((size_t)(n * 128) * 56 + (h + j)) * 56 + (w + i);
        const float* kp = kern + (size_t)f * KKDIM + ij * 128;
        for (int c = 0; c < 128; ++c) s += ip[(size_t)c * 3136] * kp[c];
    }
    out[idx] = s;
}

extern "C" void kernel_launch(void* const* d_in, const int* in_sizes, int n_in,
                              void* d_out, int out_size, void* d_ws, size_t ws_size,
                              hipStream_t stream) {
    const float* in   = (const float*)d_in[0];
    const float* kern = (const float*)d_in[1];
    float* out = (float*)d_out;

    if (ws_size < (size_t)WS_NEED) {
        const int total = N_IMG * F_OUT * WO * HO;
        k_naive<<<(total + 255) / 256, 256, 0, stream>>>(in, kern, out);
        return;
    }

    _Float16* t2 = (_Float16*)d_ws;
    _Float16* bp = (_Float16*)((char*)d_ws + BP_OFF);

    k_transpose<<<dim3(56, 32), 256, 0, stream>>>(in, t2);
    k_weights<<<(F_OUT * KKDIM + 255) / 256, 256, 0, stream>>>(kern, bp);

    (void)hipFuncSetAttribute((const void*)k_gemm,
                              hipFuncAttributeMaxDynamicSharedMemorySize, SMEM_BYTES);
    k_gemm<<<dim3(14, 32), 512, SMEM_BYTES, stream>>>(t2, bp, out);
}

// Round 6
// 215.646 us; speedup vs baseline: 1.0091x; 1.0091x over previous
//
#include <hip/hip_runtime.h>

typedef _Float16 half8 __attribute__((ext_vector_type(8)));
typedef float f32x16 __attribute__((ext_vector_type(16)));
typedef float f32x4 __attribute__((ext_vector_type(4)));

#define N_IMG 32
#define C_IN  128
#define H_IN  56
#define W_IN  56
#define F_OUT 256
#define HO    54
#define WO    54
#define KKDIM 1152
#define NKB   18            // 1152 / 64

// ws layout: T2 (fp16, swizzled NWHC) then Bp (fp16, swizzled weights)
#define T2_BYTES (N_IMG * W_IN * H_IN * C_IN * 2)   // 25,690,112
#define BP_OFF   T2_BYTES
#define BP_BYTES (NKB * F_OUT * 64 * 2)             // 589,824
#define WS_NEED  (BP_OFF + BP_BYTES)

#define SLAB_I_STRIDE 14336        // 56 rows * 256 B
#define A_BYTES   (6 * SLAB_I_STRIDE)  // 86016 staged
// A region padded: max A-read addr = 5*14336 + 65*256 + 255 = 88575 (rows
// h>=54 read garbage; row-contained in MFMA, discarded by epilogue guard)
#define A_REGION  88576
#define B_CHUNK   32768
#define SMEM_BYTES (A_REGION + 2 * B_CHUNK)  // 154112 (needs hipFuncSetAttribute)

#define ASM_BAR() asm volatile("s_barrier" ::: "memory")

// ---------------------------------------------------------------------------
// Kernel 1: inputs NCHW fp32 -> T2[n][ww][hh][c] fp16, XOR-swizzled per row:
// within each 256B c-row, 16B block index ^= (hh & 15). One block per (n,hh).
// (unchanged from passing round — do not perturb while attributing k_gemm)
// ---------------------------------------------------------------------------
__global__ __launch_bounds__(256) void k_transpose(const float* __restrict__ in,
                                                   _Float16* __restrict__ t2) {
    __shared__ _Float16 Lt[128 * 57];
    const int n  = blockIdx.y;
    const int hh = blockIdx.x;
    const int t  = threadIdx.x;

    {
        const int ww = t & 63;
        const int c0 = t >> 6;
        if (ww < 56) {
            for (int c = c0; c < 128; c += 4)
                Lt[c * 57 + ww] = (_Float16)in[(((size_t)(n * 128 + c) * 56) + hh) * 56 + ww];
        }
    }
    __syncthreads();

    {
        const int ci  = t & 15;        // c-block of 8
        const int wwi = t >> 4;        // 0..15
        const int X   = (hh & 15) << 4;
        for (int ww = wwi; ww < 56; ww += 16) {
            union { _Float16 h[8]; int4 v; } u;
#pragma unroll
            for (int jj = 0; jj < 8; ++jj)
                u.h[jj] = Lt[(ci * 8 + jj) * 57 + ww];
            char* dst = (char*)t2 + ((size_t)((n * 56 + ww) * 56 + hh)) * 256 + ((ci * 16) ^ X);
            *(int4*)dst = u.v;
        }
    }
}

// ---------------------------------------------------------------------------
// Kernel 2: weights fp32 [F][1152] -> Bp[kb][f][kin] fp16, row swizzle (f&7)<<4
// ---------------------------------------------------------------------------
__global__ __launch_bounds__(256) void k_weights(const float* __restrict__ kern,
                                                 _Float16* __restrict__ bp) {
    const int tid = blockIdx.x * 256 + threadIdx.x;
    if (tid >= F_OUT * KKDIM) return;
    const int f = tid / KKDIM;
    const int k = tid % KKDIM;
    const int kb = k >> 6, kin = k & 63;
    const _Float16 v = (_Float16)kern[tid];
    char* dst = (char*)bp + kb * B_CHUNK + f * 128 + ((kin * 2) ^ ((f & 7) << 4));
    *(_Float16*)dst = v;
}

// ---------------------------------------------------------------------------
// Kernel 3: implicit-GEMM MFMA, v2.
// WG = (n, 4 w-cols) -> 256M(4w x 64h) x 256f, 16 waves (1024 thr):
//   wave (wm 0..3, wh 0..1, wf 0..1) owns 32h x 128f -> acc 1x4 f32x16 (64 r).
// Occupancy: 4 waves/SIMD (was 2).  Sync: T3/T4 counted-vmcnt dual-barrier
// (issue B(kb+1) -> vmcnt(2) -> s_barrier -> MFMA -> s_barrier); prefetch
// never drained to 0 in-loop.  T5 setprio around MFMA quads.
// ---------------------------------------------------------------------------
typedef const __attribute__((address_space(1))) unsigned int guint;
typedef __attribute__((address_space(3))) unsigned int luint;

__global__ __launch_bounds__(1024, 4) void k_gemm(const _Float16* __restrict__ t2,
                                                  const _Float16* __restrict__ bp,
                                                  float* __restrict__ out) {
    extern __shared__ char smem[];
    char* As  = smem;
    char* Bs0 = smem + A_REGION;
    char* Bs1 = smem + A_REGION + B_CHUNK;

    const int tid  = threadIdx.x;
    const int lane = tid & 63;
    const int wid  = tid >> 6;       // 0..15
    const int wm   = wid >> 2;       // w-col within block, 0..3
    const int wh   = (wid >> 1) & 1; // h half (32 rows)
    const int wf   = wid & 1;        // f half (128 cols)
    const int ln31 = lane & 31;
    const int kin2 = (lane >> 5) * 16;   // byte offset of lane-half within k16
    const int n  = blockIdx.y;
    const int w0 = blockIdx.x * 4;

    // ---- stage A slab (linear copy of pre-swizzled T2 chunk) ----
    int navail = 56 - w0; if (navail > 6) navail = 6;
    const int bytesA = navail * SLAB_I_STRIDE;
    const char* t2n = (const char*)t2 + (size_t)(n * 56 + w0) * 56 * 256;
    for (int o = tid * 16; o < bytesA; o += 16384)   // wave-uniform trip counts
        __builtin_amdgcn_global_load_lds((guint*)(t2n + o), (luint*)(As + o), 16, 0, 0);

    // ---- stage B chunk 0 (2 loads/thread) ----
    const char* bpc = (const char*)bp;
    __builtin_amdgcn_global_load_lds((guint*)(bpc + tid * 16), (luint*)(Bs0 + tid * 16), 16, 0, 0);
    __builtin_amdgcn_global_load_lds((guint*)(bpc + tid * 16 + 16384), (luint*)(Bs0 + tid * 16 + 16384), 16, 0, 0);

    f32x16 acc[4];
#pragma unroll
    for (int ft = 0; ft < 4; ++ft)
#pragma unroll
        for (int e = 0; e < 16; ++e)
            acc[ft][e] = 0.0f;

    // NOTE: no pre-loop barrier — iteration 0's vmcnt(2)+s_barrier covers A+B0.
    const int Xb = (ln31 & 7) << 4;
    const int fb128 = (wf * 128 + ln31) * 128;   // byte row base of B frag ft=0

    for (int kb = 0; kb < NKB; ++kb) {
        const char* curB = (kb & 1) ? Bs1 : Bs0;
        if (kb < NKB - 1) {
            // prefetch next B chunk into the buffer whose readers retired at
            // the barrier ending iteration kb-1
            char* nxtB = (kb & 1) ? Bs0 : Bs1;
            const char* src = bpc + (kb + 1) * B_CHUNK;
            __builtin_amdgcn_global_load_lds((guint*)(src + tid * 16), (luint*)(nxtB + tid * 16), 16, 0, 0);
            __builtin_amdgcn_global_load_lds((guint*)(src + tid * 16 + 16384), (luint*)(nxtB + tid * 16 + 16384), 16, 0, 0);
            asm volatile("s_waitcnt vmcnt(2)" ::: "memory");  // kb's loads done; kb+1's in flight
        } else {
            asm volatile("s_waitcnt vmcnt(0)" ::: "memory");
        }
        ASM_BAR();   // all waves' B(kb) (and, at kb=0, the A slab) resident

        const int ij  = kb >> 1;
        const int iq  = ij / 3;            // w-offset
        const int jq  = ij - iq * 3;       // h-offset
        const int ch2 = (kb & 1) * 128;    // c byte offset of this 64-k chunk
        const int hh  = wh * 32 + ln31 + jq;
        const int Xa  = (hh & 15) << 4;
        const int abase = (wm + iq) * SLAB_I_STRIDE + hh * 256;

#pragma unroll
        for (int s = 0; s < 4; ++s) {
            const int cb = ch2 + s * 32 + kin2;   // byte offset within 256B c-row
            half8 aF = *(const half8*)(As + abase + (cb ^ Xa));
            half8 bF[4];
#pragma unroll
            for (int ft = 0; ft < 4; ++ft)
                bF[ft] = *(const half8*)(curB + fb128 + ft * 32 * 128 + ((s * 32 + kin2) ^ Xb));
            __builtin_amdgcn_s_setprio(1);
#pragma unroll
            for (int ft = 0; ft < 4; ++ft)
                acc[ft] = __builtin_amdgcn_mfma_f32_32x32x16_f16(aF, bF[ft], acc[ft], 0, 0, 0);
            __builtin_amdgcn_s_setprio(0);
        }
        ASM_BAR();   // reads of curB retired; next iteration may overwrite it
    }

    // ---- epilogue: C/D layout col=lane&31(f), row=(reg&3)+8*(reg>>2)+4*(lane>>5)
    const int w = w0 + wm;
    if (w < WO) {
        const int hi4 = (lane >> 5) * 4;
#pragma unroll
        for (int ft = 0; ft < 4; ++ft) {
            const int f = wf * 128 + ft * 32 + ln31;
            float* op = out + ((size_t)(n * 256 + f) * 54 + w) * 54;
#pragma unroll
            for (int q = 0; q < 4; ++q) {
                const int hb = wh * 32 + q * 8 + hi4;
                if (hb + 3 < HO) {
                    f32x4 v = { acc[ft][4 * q + 0], acc[ft][4 * q + 1],
                                acc[ft][4 * q + 2], acc[ft][4 * q + 3] };
                    *(f32x4*)(op + hb) = v;
                } else if (hb < HO) {   // hb == 52
                    op[hb]     = acc[ft][4 * q + 0];
                    op[hb + 1] = acc[ft][4 * q + 1];
                }
            }
        }
    }
}

// ---------------------------------------------------------------------------
// Fallback (only if ws too small): naive direct conv, correct but slow.
// ---------------------------------------------------------------------------
__global__ __launch_bounds__(256) void k_naive(const float* __restrict__ in,
                                               const float* __restrict__ kern,
                                               float* __restrict__ out) {
    const int idx = blockIdx.x * 256 + threadIdx.x;
    const int total = N_IMG * F_OUT * WO * HO;
    if (idx >= total) return;
    const int h = idx % 54;
    const int w = (idx / 54) % 54;
    const int f = (idx / (54 * 54)) % 256;
    const int n = idx / (54 * 54 * 256);
    float s = 0.f;
    for (int ij = 0; ij < 9; ++ij) {
        const int i = ij / 3, j = ij % 3;
        const float* ip = in + ((size_t)(n * 128) * 56 + (h + j)) * 56 + (w + i);
        const float* kp = kern + (size_t)f * KKDIM + ij * 128;
        for (int c = 0; c < 128; ++c) s += ip[(size_t)c * 3136] * kp[c];
    }
    out[idx] = s;
}

extern "C" void kernel_launch(void* const* d_in, const int* in_sizes, int n_in,
                              void* d_out, int out_size, void* d_ws, size_t ws_size,
                              hipStream_t stream) {
    const float* in   = (const float*)d_in[0];
    const float* kern = (const float*)d_in[1];
    float* out = (float*)d_out;

    if (ws_size < (size_t)WS_NEED) {
        const int total = N_IMG * F_OUT * WO * HO;
        k_naive<<<(total + 255) / 256, 256, 0, stream>>>(in, kern, out);
        return;
    }

    _Float16* t2 = (_Float16*)d_ws;
    _Float16* bp = (_Float16*)((char*)d_ws + BP_OFF);

    k_transpose<<<dim3(56, 32), 256, 0, stream>>>(in, t2);
    k_weights<<<(F_OUT * KKDIM + 255) / 256, 256, 0, stream>>>(kern, bp);

    (void)hipFuncSetAttribute((const void*)k_gemm,
                              hipFuncAttributeMaxDynamicSharedMemorySize, SMEM_BYTES);
    k_gemm<<<dim3(14, 32), 1024, SMEM_BYTES, stream>>>(t2, bp, out);
}